// Round 11
// baseline (56.992 us; speedup 1.0000x reference)
//
#include <hip/hip_runtime.h>

#define NH   8
#define SEQ  2048
#define DIM  512
#define EMB  512
#define DH   64
#define HALF 128
#define QT   16
#define KW   272          // QT + 2*HALF
#define SCS  276          // Sc row stride (f32)

typedef __attribute__((ext_vector_type(8))) short short8;
typedef __attribute__((ext_vector_type(4))) float f32x4;

__device__ __forceinline__ unsigned short f2bf(float f) {
    unsigned int u = __float_as_uint(f);
    return (unsigned short)((u + 0x7fffu + ((u >> 16) & 1u)) >> 16);
}

// packed f32x2 -> bf16x2 (RNE)
__device__ __forceinline__ unsigned cvtpk(float lo, float hi) {
    unsigned r;
    asm("v_cvt_pk_bf16_f32 %0, %1, %2" : "=v"(r) : "v"(lo), "v"(hi));
    return r;
}

__device__ __forceinline__ void gload_lds16(const void* g, void* l) {
    __builtin_amdgcn_global_load_lds((__attribute__((address_space(1))) void*)g,
                                     (__attribute__((address_space(3))) void*)l,
                                     16, 0, 0);
}

// qkv projection, f32 inputs converted inline during staging.
// 128x64 tiles, BK=64, 768 blocks, XCD-swizzled, double-buffered LDS with
// ONE barrier per K-iter: write buf[cur] -> barrier -> issue next loads ->
// compute buf[cur]  (loads land under MFMA; drain happens after compute).
__global__ __launch_bounds__(256)
void gemm_qkv(const float* __restrict__ A, const float* __restrict__ B,
              const float* __restrict__ bias, unsigned short* __restrict__ qkvh,
              unsigned short* __restrict__ vT) {
    constexpr int BM = 128, BN = 64, BK = 64;
    __shared__ unsigned short As[2][BM * BK];   // 2 x 16 KB, swizzled
    __shared__ unsigned short Bs[2][BN * BK];   // 2 x 8 KB,  swizzled
    const int bid = blockIdx.x;
    const int wg = (bid & 7) * 96 + (bid >> 3);     // XCD-local A panels
    const int bm = (wg / 24) * BM, bn = (wg % 24) * BN;
    const int t = threadIdx.x, lane = t & 63, wid = t >> 6;
    const int wr = wid >> 1, wc = wid & 1;
    const int lr = lane & 15, lg = lane >> 4;

    f32x4 acc[4][2];
    #pragma unroll
    for (int m = 0; m < 4; ++m)
        #pragma unroll
        for (int n = 0; n < 2; ++n)
            acc[m][n] = (f32x4){0.f, 0.f, 0.f, 0.f};

    float4 rA[4][2], rB[2][2];
    auto loadA = [&](int kt) {
        #pragma unroll
        for (int i = 0; i < 4; ++i) {
            const int c = t + 256 * i, r = c >> 3, c8 = c & 7;
            const float4* s = (const float4*)(A + (size_t)(bm + r) * DIM + kt + c8 * 8);
            rA[i][0] = s[0]; rA[i][1] = s[1];
        }
    };
    auto loadB = [&](int kt) {
        #pragma unroll
        for (int i = 0; i < 2; ++i) {
            const int c = t + 256 * i, r = c >> 3, c8 = c & 7;
            const float4* s = (const float4*)(B + (size_t)(bn + r) * DIM + kt + c8 * 8);
            rB[i][0] = s[0]; rB[i][1] = s[1];
        }
    };

    loadA(0); loadB(0);
    for (int it = 0; it < 8; ++it) {
        const int cur = it & 1;
        // write staged regs -> buf[cur] (cvt_pk + swizzled b128 writes)
        #pragma unroll
        for (int i = 0; i < 4; ++i) {
            const int c = t + 256 * i, r = c >> 3, c8 = c & 7;
            const uint4 pk = make_uint4(cvtpk(rA[i][0].x, rA[i][0].y), cvtpk(rA[i][0].z, rA[i][0].w),
                                        cvtpk(rA[i][1].x, rA[i][1].y), cvtpk(rA[i][1].z, rA[i][1].w));
            *(uint4*)&As[cur][r * 64 + ((c8 ^ (r & 7)) << 3)] = pk;
        }
        #pragma unroll
        for (int i = 0; i < 2; ++i) {
            const int c = t + 256 * i, r = c >> 3, c8 = c & 7;
            const uint4 pk = make_uint4(cvtpk(rB[i][0].x, rB[i][0].y), cvtpk(rB[i][0].z, rB[i][0].w),
                                        cvtpk(rB[i][1].x, rB[i][1].y), cvtpk(rB[i][1].z, rB[i][1].w));
            *(uint4*)&Bs[cur][r * 64 + ((c8 ^ (r & 7)) << 3)] = pk;
        }
        __syncthreads();
        if (it < 7) { loadA((it + 1) * BK); loadB((it + 1) * BK); }   // hide under MFMA

        short8 af[2][4], bf[2][2];
        #pragma unroll
        for (int kk = 0; kk < 2; ++kk) {
            #pragma unroll
            for (int m = 0; m < 4; ++m) {
                const int row = wr * 64 + m * 16 + lr;
                af[kk][m] = *(const short8*)&As[cur][row * 64 + (((kk * 4 + lg) ^ (row & 7)) << 3)];
            }
            #pragma unroll
            for (int n = 0; n < 2; ++n) {
                const int row = wc * 32 + n * 16 + lr;
                bf[kk][n] = *(const short8*)&Bs[cur][row * 64 + (((kk * 4 + lg) ^ (row & 7)) << 3)];
            }
        }
        #pragma unroll
        for (int kk = 0; kk < 2; ++kk)
            #pragma unroll
            for (int m = 0; m < 4; ++m)
                #pragma unroll
                for (int n = 0; n < 2; ++n)
                    acc[m][n] = __builtin_amdgcn_mfma_f32_16x16x32_bf16(af[kk][m], bf[kk][n], acc[m][n], 0, 0, 0);
    }
    __syncthreads();   // all frag reads done before Tr overwrites As

    // epilogue: acc -> Tr[128][72] bf16 (reuse As storage), then packed stores
    unsigned short* Tr = &As[0][0];
    #pragma unroll
    for (int n = 0; n < 2; ++n) {
        const int cl = wc * 32 + n * 16 + lr;
        const float bv = bias[bn + cl];
        #pragma unroll
        for (int m = 0; m < 4; ++m)
            #pragma unroll
            for (int r = 0; r < 4; ++r)
                Tr[(wr * 64 + m * 16 + lg * 4 + r) * 72 + cl] = f2bf(acc[m][n][r] + bv);
    }
    __syncthreads();

    const int h = bn / 192, ty = (bn >> 6) % 3;
    const int bb = bm >> 11, s0 = bm & 2047;
    if (ty < 2) {   // Q,K: contiguous [s][d] rows
        unsigned short* plane = qkvh + (((size_t)(bb * NH + h) * 3 + ty) * SEQ) * DH;
        const int s = t >> 1, hf = (t & 1) * 32;
        unsigned short* dst = plane + (size_t)(s0 + s) * DH + hf;
        #pragma unroll
        for (int k8 = 0; k8 < 4; ++k8)
            *(short8*)&dst[k8 * 8] = *(const short8*)&Tr[s * 72 + hf + k8 * 8];
    } else {        // V: transposed packed [d][s] stores
        const int d = t >> 2, pp = t & 3;
        unsigned short* vrow = vT + ((size_t)(bb * NH + h) * DH + d) * SEQ + s0 + pp * 32;
        #pragma unroll
        for (int k8 = 0; k8 < 4; ++k8) {
            alignas(16) unsigned short tmp[8];
            #pragma unroll
            for (int k = 0; k < 8; ++k) tmp[k] = Tr[(pp * 32 + k8 * 8 + k) * 72 + d];
            *(short8*)&vrow[k8 * 8] = *(short8*)tmp;
        }
    }
}

// MFMA windowed attention, LDS-minimal (unchanged from R10).
__global__ __launch_bounds__(256)
void attn_mfma(const unsigned short* __restrict__ qkvh,
               const unsigned short* __restrict__ vT,
               const int* __restrict__ pad,
               unsigned short* __restrict__ Yb) {
    const int bid = blockIdx.x;
    const int wg = (bid & 7) * 256 + (bid >> 3);     // XCD-local K/V planes
    const int bh = wg >> 7, qt = wg & 127;
    const int b = bh >> 3, h = bh & 7;
    const int i0 = qt * QT, kb = i0 - HALF;
    const int t = threadIdx.x, lane = t & 63, w = t >> 6;
    const int lr = lane & 15, lg = lane >> 4;

    __shared__ float Sc[QT * SCS];

    const unsigned short* Qg = qkvh + ((size_t)bh * 3 + 0) * SEQ * DH;
    const unsigned short* Kg = qkvh + ((size_t)bh * 3 + 1) * SEQ * DH;
    const unsigned short* vTg = vT + (size_t)bh * DH * SEQ;
    const int* padb = pad + b * SEQ;

    short8 qf[2];
    #pragma unroll
    for (int kk = 0; kk < 2; ++kk)
        qf[kk] = *(const short8*)&Qg[(size_t)(i0 + lr) * DH + kk * 32 + lg * 8];

    const int k0 = w * 16;
    #pragma unroll
    for (int c = 0; c < 5; ++c) {
        const int nc = (c < 4) ? 64 : 16;
        if (k0 < nc) {
            const int jl = c * 64 + k0 + lr;
            const int j = kb + jl;
            const int jc = j < 0 ? 0 : (j > SEQ - 1 ? SEQ - 1 : j);
            const int kv = (j >= 0 && j < SEQ) ? padb[j] : 0;
            f32x4 a0 = (f32x4){0.f, 0.f, 0.f, 0.f};
            #pragma unroll
            for (int kk = 0; kk < 2; ++kk) {
                const short8 bfr = *(const short8*)&Kg[(size_t)jc * DH + kk * 32 + lg * 8];
                a0 = __builtin_amdgcn_mfma_f32_16x16x32_bf16(qf[kk], bfr, a0, 0, 0, 0);
            }
            #pragma unroll
            for (int r = 0; r < 4; ++r) {
                const int q0 = lg * 4 + r;
                const bool ok = kv && (jl >= q0) && (jl <= q0 + 2 * HALF);
                Sc[q0 * SCS + jl] = ok ? a0[r] * 0.125f : -1e30f;
            }
        }
    }
    __syncthreads();

    for (int r = w; r < QT; r += 4) {
        float* row = &Sc[r * SCS];
        unsigned short* prow = (unsigned short*)row;
        if (!padb[i0 + r]) {
            #pragma unroll
            for (int u = 0; u < 5; ++u) {
                const int jl = lane + 64 * u;
                if (jl < KW) prow[jl] = 0;
            }
            if (lane >= 16 && lane < 32) prow[256 + lane] = 0;
            continue;
        }
        float v[5];
        float mx = -1e30f;
        #pragma unroll
        for (int u = 0; u < 5; ++u) {
            const int jl = lane + 64 * u;
            v[u] = (jl < KW) ? row[jl] : -1e30f;
            mx = fmaxf(mx, v[u]);
        }
        #pragma unroll
        for (int off = 32; off; off >>= 1) mx = fmaxf(mx, __shfl_xor(mx, off));
        float s = 0.f;
        #pragma unroll
        for (int u = 0; u < 5; ++u) { v[u] = __expf(v[u] - mx); s += v[u]; }
        #pragma unroll
        for (int off = 32; off; off >>= 1) s += __shfl_xor(s, off);
        const float inv = 1.f / s;
        asm volatile("" ::: "memory");
        #pragma unroll
        for (int u = 0; u < 5; ++u) {
            const int jl = lane + 64 * u;
            if (jl < KW) prow[jl] = f2bf(v[u] * inv);
        }
        if (lane >= 16 && lane < 32) prow[256 + lane] = 0;
    }
    __syncthreads();

    f32x4 o0 = (f32x4){0.f, 0.f, 0.f, 0.f};
    const unsigned short* PbU = (const unsigned short*)Sc;
    const int d0 = w * 16 + lr;
    #pragma unroll
    for (int c = 0; c < 5; ++c) {
        const int nkk = (c < 4) ? 2 : 1;
        #pragma unroll
        for (int kk = 0; kk < nkk; ++kk) {
            int j0 = kb + c * 64 + kk * 32 + lg * 8;
            j0 = j0 < 0 ? 0 : (j0 > SEQ - 8 ? SEQ - 8 : j0);
            const short8 vf = *(const short8*)&vTg[(size_t)d0 * SEQ + j0];
            const short8 pf = *(const short8*)&PbU[lr * (SCS * 2) + c * 64 + kk * 32 + lg * 8];
            o0 = __builtin_amdgcn_mfma_f32_16x16x32_bf16(pf, vf, o0, 0, 0, 0);
        }
    }

    #pragma unroll
    for (int r = 0; r < 4; ++r)
        Yb[(size_t)(b * SEQ + i0 + lg * 4 + r) * EMB + h * DH + d0] = f2bf(o0[r]);
}

// out = Yb(bf16) @ Wo(f32, inline cvt)^T + bo. 64x64 tiles, 512 blocks,
// double-buffered: A via global_load_lds into buf^1 issued post-barrier,
// B reg-staged f32->cvt; one barrier per K-iter.
__global__ __launch_bounds__(256)
void gemm_out(const unsigned short* __restrict__ A, const float* __restrict__ B,
              const float* __restrict__ bias, float* __restrict__ C) {
    constexpr int BM = 64, BN = 64, BK = 64;
    __shared__ unsigned short As[2][BM * BK];   // 2 x 8 KB
    __shared__ unsigned short Bs[2][BN * BK];   // 2 x 8 KB
    const int bid = blockIdx.x;
    const int wg = (bid & 7) * 64 + (bid >> 3);      // XCD-local A panels
    const int bm = (wg >> 3) * BM, bn = (wg & 7) * BN;
    const int t = threadIdx.x, lane = t & 63, wid = t >> 6;
    const int wr = wid >> 1, wc = wid & 1;
    const int lr = lane & 15, lg = lane >> 4;

    f32x4 acc[2][2];
    #pragma unroll
    for (int m = 0; m < 2; ++m)
        #pragma unroll
        for (int n = 0; n < 2; ++n)
            acc[m][n] = (f32x4){0.f, 0.f, 0.f, 0.f};

    float4 rB[2][2];
    auto gloadA = [&](int kt, int buf) {
        #pragma unroll
        for (int off = 0; off < BM * BK; off += 2048) {
            const int e = off + t * 8, r = e >> 6, c4 = (e & 63) >> 3;
            const int gc = (c4 ^ (r & 7)) << 3;
            gload_lds16(A + (size_t)(bm + r) * EMB + kt + gc, &As[buf][e]);
        }
    };
    auto loadB = [&](int kt) {
        #pragma unroll
        for (int i = 0; i < 2; ++i) {
            const int c = t + 256 * i, r = c >> 3, c8 = c & 7;
            const float4* s = (const float4*)(B + (size_t)(bn + r) * DIM + kt + c8 * 8);
            rB[i][0] = s[0]; rB[i][1] = s[1];
        }
    };

    gloadA(0, 0);
    loadB(0);
    for (int it = 0; it < 8; ++it) {
        const int cur = it & 1;
        #pragma unroll
        for (int i = 0; i < 2; ++i) {
            const int c = t + 256 * i, r = c >> 3, c8 = c & 7;
            const uint4 pk = make_uint4(cvtpk(rB[i][0].x, rB[i][0].y), cvtpk(rB[i][0].z, rB[i][0].w),
                                        cvtpk(rB[i][1].x, rB[i][1].y), cvtpk(rB[i][1].z, rB[i][1].w));
            *(uint4*)&Bs[cur][r * 64 + ((c8 ^ (r & 7)) << 3)] = pk;
        }
        __syncthreads();    // drains gloadA->As[cur] + Bs[cur] writes
        if (it < 7) { gloadA((it + 1) * BK, cur ^ 1); loadB((it + 1) * BK); }

        short8 af[2][2], bf[2][2];
        #pragma unroll
        for (int kk = 0; kk < 2; ++kk) {
            #pragma unroll
            for (int m = 0; m < 2; ++m) {
                const int row = wr * 32 + m * 16 + lr;
                af[kk][m] = *(const short8*)&As[cur][row * BK + (((kk * 4 + lg) ^ (row & 7)) << 3)];
            }
            #pragma unroll
            for (int n = 0; n < 2; ++n) {
                const int row = wc * 32 + n * 16 + lr;
                bf[kk][n] = *(const short8*)&Bs[cur][row * BK + (((kk * 4 + lg) ^ (row & 7)) << 3)];
            }
        }
        #pragma unroll
        for (int kk = 0; kk < 2; ++kk)
            #pragma unroll
            for (int m = 0; m < 2; ++m)
                #pragma unroll
                for (int n = 0; n < 2; ++n)
                    acc[m][n] = __builtin_amdgcn_mfma_f32_16x16x32_bf16(af[kk][m], bf[kk][n], acc[m][n], 0, 0, 0);
    }

    const int orow = bm + wr * 32 + lg * 4;
    const int oc0 = bn + wc * 32 + lr;
    #pragma unroll
    for (int m = 0; m < 2; ++m)
        #pragma unroll
        for (int n = 0; n < 2; ++n) {
            const int col = oc0 + n * 16;
            const float bv = bias[col];
            #pragma unroll
            for (int r = 0; r < 4; ++r)
                C[(size_t)(orow + m * 16 + r) * EMB + col] = acc[m][n][r] + bv;
        }
}

extern "C" void kernel_launch(void* const* d_in, const int* in_sizes, int n_in,
                              void* d_out, int out_size, void* d_ws, size_t ws_size,
                              hipStream_t stream) {
    const float* x    = (const float*)d_in[0];
    const int*   pad  = (const int*)d_in[1];
    const float* Wqkv = (const float*)d_in[2];
    const float* bqkv = (const float*)d_in[3];
    const float* Wo   = (const float*)d_in[4];
    const float* bo   = (const float*)d_in[5];
    float* out = (float*)d_out;

    char* p = (char*)d_ws;
    unsigned short* qkvh = (unsigned short*)p;                   // 12.6 MB (Q,K planes)
    unsigned short* vT   = (unsigned short*)(p + 12582912);      // 4 MB
    unsigned short* Yb   = (unsigned short*)(p + 16777216);      // 4 MB

    dim3 blk(256);
    gemm_qkv<<<dim3(768), blk, 0, stream>>>(x, Wqkv, bqkv, qkvh, vT);
    attn_mfma<<<dim3(2048), blk, 0, stream>>>(qkvh, vT, pad, Yb);
    gemm_out<<<dim3(512), blk, 0, stream>>>(Yb, Wo, bo, out);
}